// Round 7
// baseline (308.948 us; speedup 1.0000x reference)
//
#include <hip/hip_runtime.h>
#include <hip/hip_bf16.h>

#define M_   16384   // B*N tokens
#define K_   1024    // E
#define NQKV 3072    // 3*E output cols

typedef _Float16 f16x4 __attribute__((ext_vector_type(4)));
typedef _Float16 f16x8 __attribute__((ext_vector_type(8)));
typedef float    f32x4 __attribute__((ext_vector_type(4)));

// fp32 -> fp16 grid-stride convert (float4 granularity)
__global__ __launch_bounds__(256) void cvt_f32_f16(const float* __restrict__ in,
                                                   _Float16* __restrict__ o, int n4) {
  int i = blockIdx.x * blockDim.x + threadIdx.x;
  const int stride = gridDim.x * blockDim.x;
  for (; i < n4; i += stride) {
    float4 v = ((const float4*)in)[i];
    f16x4 h; h[0] = (_Float16)v.x; h[1] = (_Float16)v.y;
    h[2] = (_Float16)v.z; h[3] = (_Float16)v.w;
    *(f16x4*)&o[(size_t)i * 4] = h;
  }
}

// 3 weight matrices in one launch (blockIdx.y selects source)
__global__ __launch_bounds__(256) void cvt3_f32_f16(
    const float* __restrict__ a, const float* __restrict__ b,
    const float* __restrict__ c, _Float16* __restrict__ o, int n4each) {
  const float* src = (blockIdx.y == 0) ? a : (blockIdx.y == 1) ? b : c;
  _Float16* dst = o + (size_t)blockIdx.y * n4each * 4;
  int i = blockIdx.x * blockDim.x + threadIdx.x;
  const int stride = gridDim.x * blockDim.x;
  for (; i < n4each; i += stride) {
    float4 v = ((const float4*)src)[i];
    f16x4 h; h[0] = (_Float16)v.x; h[1] = (_Float16)v.y;
    h[2] = (_Float16)v.z; h[3] = (_Float16)v.w;
    *(f16x4*)&dst[(size_t)i * 4] = h;
  }
}

// 256x256-tile GEMM, register-neutral fragment prefetch, 2 barriers/K-tile.
// Quadrant order (a0,b0)->(a1,b0)->(a1,b1)->(a0,b1). Each register set is
// refilled IN PLACE during the window after its last use (in-order issue
// makes the WAR safe; no extra buffers -> no R5 spill):
//   q1: MFMA(a0,b0) || read b1(t), issue all 8 gload_lds for t+1
//   q2: MFMA(a1,b0) || nothing     -> VM0 + BarA  (staging visible to all)
//   q3: MFMA(a1,b1) || read b0(t+1) from buf^1    (b0 dead after q2)
//   q4: MFMA(a0,b1) || read a1(t+1) from buf^1    (a1 dead after q3)
//   BarB; next tile starts with serial read a0(t+1) + lgkm(0) (~220 cyc).
// Ledger: buf^1 overwrite (stage at q1(t)) is >=2 barriers after buf^1's last
// read (b1(t-1) at q1(t-1)); cross-wave reads of staged data (b0'/a1' at
// q3/q4, a0' at next tile start) are behind all-waves VM0+BarA / BarB.
// Stage order A0,B0,A1,B1; VM0 at BarA (~1250cyc after issue > 900 HBM lat).
// Per-tile floor: max(LDS 2816, MFMA 2483) + ~220 + 2 bars ~= 3100 cyc
// (was 5870 with the 8-barrier phase-lockstep structure).
// Epilogue: nh innermost (full-128B-line writes; R6 verified -34MB WRITE_SIZE).
__global__ __launch_bounds__(512, 2) void gemm_qkv(
    const _Float16* __restrict__ xh, const _Float16* __restrict__ wh,
    const float* __restrict__ bq, const float* __restrict__ bk,
    const float* __restrict__ bv, _Float16* __restrict__ qkv)
{
  __shared__ __align__(16) _Float16 As[2][256 * 64];
  __shared__ __align__(16) _Float16 Bs[2][256 * 64];

  const int tid  = threadIdx.x;
  const int ln   = tid & 63;
  const int w    = tid >> 6;     // 0..7
  const int wm2  = w >> 2;       // 0..1
  const int wn4  = w & 3;        // 0..3
  const int lcol = ln & 15, quad = ln >> 4;

  const int bid = blockIdx.x;                   // 768 blocks
  const int swz = (bid & 7) * 96 + (bid >> 3);  // XCD-contiguous chunks
  const int m0 = (swz / 12) * 256;
  const int n0 = (swz % 12) * 256;

  f32x4 acc[8][4];
#pragma unroll
  for (int i = 0; i < 8; ++i)
#pragma unroll
    for (int j = 0; j < 4; ++j) acc[i][j] = f32x4{0.f, 0.f, 0.f, 0.f};

  f16x8 a0[4][2], a1[4][2], b0[2][2], b1[2][2];   // 96 VGPR, same as R3/R6

#define STAGE_A(BUF, KT, X)                                                    \
  { _Pragma("unroll")                                                          \
    for (int j = 0; j < 2; ++j) {                                              \
      const int c   = j * 512 + tid;                                           \
      const int rr  = c >> 3;                                                  \
      const int r   = (X) * 64 + (rr & 63) + ((rr >> 6) << 7);                 \
      const int cb  = (c & 7) ^ (r & 7);                                       \
      const int rr0 = j * 64 + w * 8;                                          \
      const int r0  = (X) * 64 + (rr0 & 63) + ((rr0 >> 6) << 7);               \
      __builtin_amdgcn_global_load_lds(                                        \
          (const __attribute__((address_space(1))) void*)(                     \
              xh + (size_t)(m0 + r) * K_ + (KT) * 64 + cb * 8),                \
          (__attribute__((address_space(3))) void*)(&As[BUF][r0 * 64]),        \
          16, 0, 0);                                                           \
    } }

#define STAGE_B(BUF, KT, Y)                                                    \
  { _Pragma("unroll")                                                          \
    for (int j = 0; j < 2; ++j) {                                              \
      const int c   = j * 512 + tid;                                           \
      const int rr  = c >> 3;                                                  \
      const int r   = ((rr >> 5) << 6) + (Y) * 32 + (rr & 31);                 \
      const int cb  = (c & 7) ^ (r & 7);                                       \
      const int rr0 = j * 64 + w * 8;                                          \
      const int r0  = ((rr0 >> 5) << 6) + (Y) * 32 + (rr0 & 31);               \
      __builtin_amdgcn_global_load_lds(                                        \
          (const __attribute__((address_space(1))) void*)(                     \
              wh + (size_t)(n0 + r) * K_ + (KT) * 64 + cb * 8),                \
          (__attribute__((address_space(3))) void*)(&Bs[BUF][r0 * 64]),        \
          16, 0, 0);                                                           \
    } }

  // full-half fragment reads (both k-blocks): A-half = 8 b128, B-half = 4
#define RDA(DST, BUF, MH)                                                      \
  _Pragma("unroll")                                                            \
  for (int mi = 0; mi < 4; ++mi) {                                             \
    const int ar = wm2 * 128 + (MH) * 64 + mi * 16 + lcol;                     \
    const int sw = ar & 7;                                                     \
    DST[mi][0] = *(const f16x8*)&As[BUF][ar * 64 + ((quad    ) ^ sw) * 8];     \
    DST[mi][1] = *(const f16x8*)&As[BUF][ar * 64 + ((quad + 4) ^ sw) * 8];     \
  }

#define RDB(DST, BUF, NH)                                                      \
  _Pragma("unroll")                                                            \
  for (int ni = 0; ni < 2; ++ni) {                                             \
    const int br = wn4 * 64 + (NH) * 32 + ni * 16 + lcol;                      \
    const int sw = br & 7;                                                     \
    DST[ni][0] = *(const f16x8*)&Bs[BUF][br * 64 + ((quad    ) ^ sw) * 8];     \
    DST[ni][1] = *(const f16x8*)&Bs[BUF][br * 64 + ((quad + 4) ^ sw) * 8];     \
  }

  // one C-quadrant x K=64: 16 MFMAs
#define MFMA16(AARR, BARR, MH, NH)                                             \
  __builtin_amdgcn_s_setprio(1);                                               \
  _Pragma("unroll")                                                            \
  for (int kb = 0; kb < 2; ++kb)                                               \
    _Pragma("unroll")                                                          \
    for (int mi = 0; mi < 4; ++mi)                                             \
      _Pragma("unroll")                                                        \
      for (int ni = 0; ni < 2; ++ni)                                           \
        acc[(MH) * 4 + mi][(NH) * 2 + ni] =                                    \
            __builtin_amdgcn_mfma_f32_16x16x32_f16(                            \
                AARR[mi][kb], BARR[ni][kb], acc[(MH) * 4 + mi][(NH) * 2 + ni], \
                0, 0, 0);                                                      \
  __builtin_amdgcn_s_setprio(0);

#define SB()    __builtin_amdgcn_sched_barrier(0)
#define BAR()   { __builtin_amdgcn_s_barrier(); SB(); }
#define LGKM0() { asm volatile("s_waitcnt lgkmcnt(0)" ::: "memory"); SB(); }
#define VM0()   { asm volatile("s_waitcnt vmcnt(0)" ::: "memory"); SB(); }

#define KTILE(CUR, T, NOTLAST)                                                 \
  { /* serial: a0(t) (its regs freed only at q4 of t-1) */                     \
    RDA(a0, CUR, 0); SB();                                                     \
    LGKM0();  /* drains a0(t) + prefetched b0(t), a1(t) */                     \
    /* q1: MFMA(a0,b0) || b1(t) reads + all staging for t+1 */                 \
    RDB(b1, CUR, 1); SB();                                                     \
    if (NOTLAST) {                                                             \
      STAGE_A(1 - (CUR), (T) + 1, 0); STAGE_B(1 - (CUR), (T) + 1, 0);          \
      STAGE_A(1 - (CUR), (T) + 1, 1); STAGE_B(1 - (CUR), (T) + 1, 1);          \
      SB();                                                                    \
    }                                                                          \
    MFMA16(a0, b0, 0, 0);                                                      \
    /* q2: operands already resident */                                        \
    MFMA16(a1, b0, 1, 0);                                                      \
    if (NOTLAST) VM0();                                                        \
    BAR();  /* BarA: staged t+1 visible to all waves */                        \
    /* q3: needs b1 (issued under q1, long done) || prefetch b0(t+1) */        \
    LGKM0();                                                                   \
    if (NOTLAST) { RDB(b0, 1 - (CUR), 0); SB(); }                              \
    MFMA16(a1, b1, 1, 1);                                                      \
    /* q4: || prefetch a1(t+1) */                                              \
    if (NOTLAST) { RDA(a1, 1 - (CUR), 1); SB(); }                              \
    MFMA16(a0, b1, 0, 1);                                                      \
    BAR();  /* BarB */                                                         \
  }

  // Prologue: stage tile0 fully; prefetch b0(t0), a1(t0) (loop reads a0 itself)
  STAGE_A(0, 0, 0); STAGE_B(0, 0, 0); STAGE_A(0, 0, 1); STAGE_B(0, 0, 1);
  VM0(); BAR();
  RDB(b0, 0, 0); SB(); RDA(a1, 0, 1); SB();

#pragma unroll 1
  for (int it = 0; it < 7; ++it) {
    KTILE(0, it * 2,     1);
    KTILE(1, it * 2 + 1, 1);
  }
  KTILE(0, 14, 1);
  KTILE(1, 15, 0);

  // Epilogue. C/D: col=lane&15, row=quad*4+reg. mi -> r -> nh: a quad's 4
  // nh-stores (32B each) are back-to-back covering one 128B line.
  float bi4[4];
#pragma unroll
  for (int nh = 0; nh < 4; ++nh) {
    const int col = n0 + wn4 * 64 + nh * 16 + lcol;
    const int seg = col >> 10, cs = col & 1023;
    bi4[nh] = ((seg == 0) ? bq : (seg == 1) ? bk : bv)[cs];
  }
#pragma unroll
  for (int mi = 0; mi < 8; ++mi) {
    const int r0 = m0 + wm2 * 128 + mi * 16 + quad * 4;
#pragma unroll
    for (int r = 0; r < 4; ++r) {
      _Float16* rowp = qkv + (size_t)(r0 + r) * 3072 + n0 + wn4 * 64 + lcol;
#pragma unroll
      for (int nh = 0; nh < 4; ++nh)
        rowp[nh * 16] = (_Float16)(acc[mi][nh][r] + bi4[nh]);
    }
  }
#undef STAGE_A
#undef STAGE_B
#undef RDA
#undef RDB
#undef MFMA16
#undef SB
#undef BAR
#undef LGKM0
#undef VM0
#undef KTILE
}

// One wave per token. qkv [token][3][1024] fp16. All global loads hoisted;
// pat read directly from global (L2-hot, no LDS/sync); PV uses 16x16x16 MFMA
// (K=16 exact: all 64 lanes active). Output stores: dt INNERMOST so each
// quad-row's 4x64B stores are consecutive (full-line write coalescing).
__global__ __launch_bounds__(256) void attn_kernel(
    const _Float16* __restrict__ qkv,
    const float* __restrict__ pat,
    float* __restrict__ out)
{
  __shared__ __align__(16) _Float16 Ps[4][16 * 24];  // P[h][g], stride 24
  __shared__ __align__(16) _Float16 Vt[4][64 * 24];  // V^T[d][g], stride 24

  const int tid  = threadIdx.x;
  const int ln   = tid & 63;
  const int wv   = tid >> 6;
  const int lcol = ln & 15, quad = ln >> 4;
  const int t    = blockIdx.x * 4 + wv;

  const _Float16* qg = qkv + (size_t)t * 3072;
  const _Float16* kg = qg + 1024;
  const _Float16* vg = qg + 2048;

  // Issue every global load up front: V (2), Q (2), K (2), pat (4 scalar).
  f16x8 vc[2];
  vc[0] = *(const f16x8*)(vg + ((ln >> 3)    ) * 64 + (ln & 7) * 8);
  vc[1] = *(const f16x8*)(vg + ((ln >> 3) + 8) * 64 + (ln & 7) * 8);
  f16x8 aq0 = *(const f16x8*)(qg + lcol * 64 + quad * 8);
  f16x8 aq1 = *(const f16x8*)(qg + lcol * 64 + 32 + quad * 8);
  f16x8 bk0 = *(const f16x8*)(kg + lcol * 64 + quad * 8);
  f16x8 bk1 = *(const f16x8*)(kg + lcol * 64 + 32 + quad * 8);
  float p4[4];
#pragma unroll
  for (int r = 0; r < 4; r++) p4[r] = pat[(quad * 4 + r) * 16 + lcol];

  // Scatter V transposed into Vt[d][g] (wave-private, no barrier needed).
#pragma unroll
  for (int i = 0; i < 2; i++) {
    const int g = (ln >> 3) + i * 8, c = (ln & 7) * 8;
#pragma unroll
    for (int j = 0; j < 8; j++) Vt[wv][(c + j) * 24 + g] = vc[i][j];
  }

  // QK^T: A[m=h=lcol][k=quad*8+j], B[n=g=lcol][k=quad*8+j]
  f32x4 s = {0.f, 0.f, 0.f, 0.f};
  s = __builtin_amdgcn_mfma_f32_16x16x32_f16(aq0, bk0, s, 0, 0, 0);
  s = __builtin_amdgcn_mfma_f32_16x16x32_f16(aq1, bk1, s, 0, 0, 0);

  // lane holds scores[h=quad*4+r][g=lcol]; mask, softmax over g (16 lanes)
#pragma unroll
  for (int r = 0; r < 4; r++) {
    const float sv = s[r] * p4[r];
    float m = sv;
#pragma unroll
    for (int msk = 1; msk < 16; msk <<= 1) m = fmaxf(m, __shfl_xor(m, msk, 64));
    const float e = __expf(sv - m);
    float su = e;
#pragma unroll
    for (int msk = 1; msk < 16; msk <<= 1) su += __shfl_xor(su, msk, 64);
    Ps[wv][(quad * 4 + r) * 24 + lcol] = (_Float16)(e / su);
  }

  // PV with 16x16x16 (K=16): A[m=h=lcol][k=g=quad*4+j] from Ps;
  // B[n=d][k=g=quad*4+j] from Vt. All lanes active.
  f16x4 ap = *(const f16x4*)&Ps[wv][lcol * 24 + quad * 4];

  f32x4 o[4];
#pragma unroll
  for (int dt = 0; dt < 4; dt++) {
    f16x4 bvf = *(const f16x4*)&Vt[wv][(dt * 16 + lcol) * 24 + quad * 4];
    f32x4 z = {0.f, 0.f, 0.f, 0.f};
    o[dt] = __builtin_amdgcn_mfma_f32_16x16x16f16(ap, bvf, z, 0, 0, 0);
  }

  // C layout: row h=quad*4+r, col d=dt*16+lcol. dt innermost: 4 consecutive
  // 64B pieces of one 256B row region per (r).
  float* op = out + (size_t)t * 1024;
#pragma unroll
  for (int r = 0; r < 4; r++) {
    float* rp = op + (quad * 4 + r) * 64 + lcol;
#pragma unroll
    for (int dt = 0; dt < 4; dt++)
      rp[dt * 16] = o[dt][r];
  }
}

extern "C" void kernel_launch(void* const* d_in, const int* in_sizes, int n_in,
                              void* d_out, int out_size, void* d_ws, size_t ws_size,
                              hipStream_t stream) {
  const float* x   = (const float*)d_in[0];
  const float* pat = (const float*)d_in[1];
  const float* Wq  = (const float*)d_in[2];
  const float* bq  = (const float*)d_in[3];
  const float* Wk  = (const float*)d_in[4];
  const float* bk  = (const float*)d_in[5];
  const float* Wv  = (const float*)d_in[6];
  const float* bv  = (const float*)d_in[7];

  // ws layout (f16 elements):
  //   qkvh [16384][3][1024]  @ 0           (96 MiB)
  //   xh   [16384][1024]     @ 50331648    (32 MiB)
  //   wh   [3][1024][1024]   @ 67108864    ( 6 MiB)   total ~134 MiB
  _Float16* qkvh = (_Float16*)d_ws;
  _Float16* xh   = qkvh + (size_t)50331648;
  _Float16* wh   = qkvh + (size_t)67108864;

  cvt_f32_f16<<<4096, 256, 0, stream>>>(x, xh, 4194304);
  cvt3_f32_f16<<<dim3(256, 3), 256, 0, stream>>>(Wq, Wk, Wv, wh, 262144);

  // 64 m-tiles x 12 n-tiles = 768 blocks, 512 threads (8 waves)
  gemm_qkv<<<768, 512, 0, stream>>>(xh, wh, bq, bk, bv, qkvh);
  attn_kernel<<<M_ / 4, 256, 0, stream>>>(qkvh, pat, (float*)d_out);
}

// Round 8
// 297.935 us; speedup vs baseline: 1.0370x; 1.0370x over previous
//
#include <hip/hip_runtime.h>
#include <hip/hip_bf16.h>

#define M_   16384   // B*N tokens
#define K_   1024    // E
#define NQKV 3072    // 3*E output cols

typedef _Float16 f16x4 __attribute__((ext_vector_type(4)));
typedef _Float16 f16x8 __attribute__((ext_vector_type(8)));
typedef float    f32x4 __attribute__((ext_vector_type(4)));

// fp32 -> fp16 grid-stride convert (float4 granularity)
__global__ __launch_bounds__(256) void cvt_f32_f16(const float* __restrict__ in,
                                                   _Float16* __restrict__ o, int n4) {
  int i = blockIdx.x * blockDim.x + threadIdx.x;
  const int stride = gridDim.x * blockDim.x;
  for (; i < n4; i += stride) {
    float4 v = ((const float4*)in)[i];
    f16x4 h; h[0] = (_Float16)v.x; h[1] = (_Float16)v.y;
    h[2] = (_Float16)v.z; h[3] = (_Float16)v.w;
    *(f16x4*)&o[(size_t)i * 4] = h;
  }
}

// 3 weight matrices in one launch (blockIdx.y selects source)
__global__ __launch_bounds__(256) void cvt3_f32_f16(
    const float* __restrict__ a, const float* __restrict__ b,
    const float* __restrict__ c, _Float16* __restrict__ o, int n4each) {
  const float* src = (blockIdx.y == 0) ? a : (blockIdx.y == 1) ? b : c;
  _Float16* dst = o + (size_t)blockIdx.y * n4each * 4;
  int i = blockIdx.x * blockDim.x + threadIdx.x;
  const int stride = gridDim.x * blockDim.x;
  for (; i < n4each; i += stride) {
    float4 v = ((const float4*)src)[i];
    f16x4 h; h[0] = (_Float16)v.x; h[1] = (_Float16)v.y;
    h[2] = (_Float16)v.z; h[3] = (_Float16)v.w;
    *(f16x4*)&dst[(size_t)i * 4] = h;
  }
}

// 256x256-tile GEMM, single-barrier K-tile with counted lgkmcnt overlap.
// REGISTER-NEUTRAL pipelining (R5/R7 lesson: any extra fragment liveness at
// this geometry spills -> phantom FETCH/WRITE): all four fragment sets are
// already co-live in the R6 schedule at ph3, so issuing ALL 24 ds_reads at
// tile start adds zero peak liveness. Counted lgkmcnt gates each quadrant:
//   issue b0(4),a0(8),a1(8),b1(4) | stage 8 gload_lds(t+1)
//   lgkm(12) q1(a0,b0) | lgkm(4) q2(a1,b0) | lgkm(0) q3(a1,b1) q4(a0,b1)
//   VM0; BAR   (one barrier per K-tile; DS pipe drains under q1/q2 MFMAs)
// Ledger: reads of buf CUR complete before lgkm(0) -> before BAR(t); stage
// into buf^1 is after BAR(t-1) = after all waves' reads of buf^1 (WAR safe);
// staged t+1 data consumed after all-waves VM0(t)+BAR(t), VM0 ~2800cyc after
// issue >> 900cyc HBM latency (no stall).
// Epilogue: nh innermost (full-128B-line writes; R6 verified -34MB WRITE_SIZE).
__global__ __launch_bounds__(512, 2) void gemm_qkv(
    const _Float16* __restrict__ xh, const _Float16* __restrict__ wh,
    const float* __restrict__ bq, const float* __restrict__ bk,
    const float* __restrict__ bv, _Float16* __restrict__ qkv)
{
  __shared__ __align__(16) _Float16 As[2][256 * 64];
  __shared__ __align__(16) _Float16 Bs[2][256 * 64];

  const int tid  = threadIdx.x;
  const int ln   = tid & 63;
  const int w    = tid >> 6;     // 0..7
  const int wm2  = w >> 2;       // 0..1
  const int wn4  = w & 3;        // 0..3
  const int lcol = ln & 15, quad = ln >> 4;

  const int bid = blockIdx.x;                   // 768 blocks
  const int swz = (bid & 7) * 96 + (bid >> 3);  // XCD-contiguous chunks
  const int m0 = (swz / 12) * 256;
  const int n0 = (swz % 12) * 256;

  f32x4 acc[8][4];
#pragma unroll
  for (int i = 0; i < 8; ++i)
#pragma unroll
    for (int j = 0; j < 4; ++j) acc[i][j] = f32x4{0.f, 0.f, 0.f, 0.f};

  f16x8 a0[4][2], a1[4][2], b0[2][2], b1[2][2];   // 96 VGPR, same as R6

#define STAGE_A(BUF, KT, X)                                                    \
  { _Pragma("unroll")                                                          \
    for (int j = 0; j < 2; ++j) {                                              \
      const int c   = j * 512 + tid;                                           \
      const int rr  = c >> 3;                                                  \
      const int r   = (X) * 64 + (rr & 63) + ((rr >> 6) << 7);                 \
      const int cb  = (c & 7) ^ (r & 7);                                       \
      const int rr0 = j * 64 + w * 8;                                          \
      const int r0  = (X) * 64 + (rr0 & 63) + ((rr0 >> 6) << 7);               \
      __builtin_amdgcn_global_load_lds(                                        \
          (const __attribute__((address_space(1))) void*)(                     \
              xh + (size_t)(m0 + r) * K_ + (KT) * 64 + cb * 8),                \
          (__attribute__((address_space(3))) void*)(&As[BUF][r0 * 64]),        \
          16, 0, 0);                                                           \
    } }

#define STAGE_B(BUF, KT, Y)                                                    \
  { _Pragma("unroll")                                                          \
    for (int j = 0; j < 2; ++j) {                                              \
      const int c   = j * 512 + tid;                                           \
      const int rr  = c >> 3;                                                  \
      const int r   = ((rr >> 5) << 6) + (Y) * 32 + (rr & 31);                 \
      const int cb  = (c & 7) ^ (r & 7);                                       \
      const int rr0 = j * 64 + w * 8;                                          \
      const int r0  = ((rr0 >> 5) << 6) + (Y) * 32 + (rr0 & 31);               \
      __builtin_amdgcn_global_load_lds(                                        \
          (const __attribute__((address_space(1))) void*)(                     \
              wh + (size_t)(n0 + r) * K_ + (KT) * 64 + cb * 8),                \
          (__attribute__((address_space(3))) void*)(&Bs[BUF][r0 * 64]),        \
          16, 0, 0);                                                           \
    } }

  // full-half fragment reads (both k-blocks): A-half = 8 b128, B-half = 4
#define RDA(DST, BUF, MH)                                                      \
  _Pragma("unroll")                                                            \
  for (int mi = 0; mi < 4; ++mi) {                                             \
    const int ar = wm2 * 128 + (MH) * 64 + mi * 16 + lcol;                     \
    const int sw = ar & 7;                                                     \
    DST[mi][0] = *(const f16x8*)&As[BUF][ar * 64 + ((quad    ) ^ sw) * 8];     \
    DST[mi][1] = *(const f16x8*)&As[BUF][ar * 64 + ((quad + 4) ^ sw) * 8];     \
  }

#define RDB(DST, BUF, NH)                                                      \
  _Pragma("unroll")                                                            \
  for (int ni = 0; ni < 2; ++ni) {                                             \
    const int br = wn4 * 64 + (NH) * 32 + ni * 16 + lcol;                      \
    const int sw = br & 7;                                                     \
    DST[ni][0] = *(const f16x8*)&Bs[BUF][br * 64 + ((quad    ) ^ sw) * 8];     \
    DST[ni][1] = *(const f16x8*)&Bs[BUF][br * 64 + ((quad + 4) ^ sw) * 8];     \
  }

  // one C-quadrant x K=64: 16 MFMAs
#define MFMA16(AARR, BARR, MH, NH)                                             \
  __builtin_amdgcn_s_setprio(1);                                               \
  _Pragma("unroll")                                                            \
  for (int kb = 0; kb < 2; ++kb)                                               \
    _Pragma("unroll")                                                          \
    for (int mi = 0; mi < 4; ++mi)                                             \
      _Pragma("unroll")                                                        \
      for (int ni = 0; ni < 2; ++ni)                                           \
        acc[(MH) * 4 + mi][(NH) * 2 + ni] =                                    \
            __builtin_amdgcn_mfma_f32_16x16x32_f16(                            \
                AARR[mi][kb], BARR[ni][kb], acc[(MH) * 4 + mi][(NH) * 2 + ni], \
                0, 0, 0);                                                      \
  __builtin_amdgcn_s_setprio(0);

#define SB()    __builtin_amdgcn_sched_barrier(0)
#define BAR()   { __builtin_amdgcn_s_barrier(); SB(); }
#define LGKM(N) { asm volatile("s_waitcnt lgkmcnt(" #N ")" ::: "memory"); SB(); }
#define VM0()   { asm volatile("s_waitcnt vmcnt(0)" ::: "memory"); SB(); }

#define KTILE(CUR, T, NOTLAST)                                                 \
  { /* issue ALL fragment reads, counted order: b0,a0 (12) | a1 (8) | b1 (4) */\
    RDB(b0, CUR, 0); SB();                                                     \
    RDA(a0, CUR, 0); SB();                                                     \
    RDA(a1, CUR, 1); SB();                                                     \
    RDB(b1, CUR, 1); SB();                                                     \
    if (NOTLAST) {                                                             \
      STAGE_A(1 - (CUR), (T) + 1, 0); STAGE_B(1 - (CUR), (T) + 1, 0);          \
      STAGE_A(1 - (CUR), (T) + 1, 1); STAGE_B(1 - (CUR), (T) + 1, 1);          \
      SB();                                                                    \
    }                                                                          \
    LGKM(12); MFMA16(a0, b0, 0, 0);                                            \
    LGKM(4);  MFMA16(a1, b0, 1, 0);                                            \
    LGKM(0);  MFMA16(a1, b1, 1, 1);                                            \
              MFMA16(a0, b1, 0, 1);                                            \
    if (NOTLAST) { VM0(); }                                                    \
    BAR();                                                                     \
  }

  // Prologue: stage tile 0 fully, drain, barrier.
  STAGE_A(0, 0, 0); STAGE_B(0, 0, 0); STAGE_A(0, 0, 1); STAGE_B(0, 0, 1);
  VM0(); BAR();

#pragma unroll 1
  for (int it = 0; it < 7; ++it) {
    KTILE(0, it * 2,     1);
    KTILE(1, it * 2 + 1, 1);
  }
  KTILE(0, 14, 1);
  KTILE(1, 15, 0);

  // Epilogue. C/D: col=lane&15, row=quad*4+reg. mi -> r -> nh: a quad's 4
  // nh-stores (32B each) are back-to-back covering one 128B line.
  float bi4[4];
#pragma unroll
  for (int nh = 0; nh < 4; ++nh) {
    const int col = n0 + wn4 * 64 + nh * 16 + lcol;
    const int seg = col >> 10, cs = col & 1023;
    bi4[nh] = ((seg == 0) ? bq : (seg == 1) ? bk : bv)[cs];
  }
#pragma unroll
  for (int mi = 0; mi < 8; ++mi) {
    const int r0 = m0 + wm2 * 128 + mi * 16 + quad * 4;
#pragma unroll
    for (int r = 0; r < 4; ++r) {
      _Float16* rowp = qkv + (size_t)(r0 + r) * 3072 + n0 + wn4 * 64 + lcol;
#pragma unroll
      for (int nh = 0; nh < 4; ++nh)
        rowp[nh * 16] = (_Float16)(acc[mi][nh][r] + bi4[nh]);
    }
  }
#undef STAGE_A
#undef STAGE_B
#undef RDA
#undef RDB
#undef MFMA16
#undef SB
#undef BAR
#undef LGKM
#undef VM0
#undef KTILE
}

// One wave per token. qkv [token][3][1024] fp16. All global loads hoisted;
// pat read directly from global (L2-hot, no LDS/sync); PV uses 16x16x16 MFMA
// (K=16 exact: all 64 lanes active). Output stores: dt INNERMOST so each
// quad-row's 4x64B stores are consecutive (full-line write coalescing).
__global__ __launch_bounds__(256) void attn_kernel(
    const _Float16* __restrict__ qkv,
    const float* __restrict__ pat,
    float* __restrict__ out)
{
  __shared__ __align__(16) _Float16 Ps[4][16 * 24];  // P[h][g], stride 24
  __shared__ __align__(16) _Float16 Vt[4][64 * 24];  // V^T[d][g], stride 24

  const int tid  = threadIdx.x;
  const int ln   = tid & 63;
  const int wv   = tid >> 6;
  const int lcol = ln & 15, quad = ln >> 4;
  const int t    = blockIdx.x * 4 + wv;

  const _Float16* qg = qkv + (size_t)t * 3072;
  const _Float16* kg = qg + 1024;
  const _Float16* vg = qg + 2048;

  // Issue every global load up front: V (2), Q (2), K (2), pat (4 scalar).
  f16x8 vc[2];
  vc[0] = *(const f16x8*)(vg + ((ln >> 3)    ) * 64 + (ln & 7) * 8);
  vc[1] = *(const f16x8*)(vg + ((ln >> 3) + 8) * 64 + (ln & 7) * 8);
  f16x8 aq0 = *(const f16x8*)(qg + lcol * 64 + quad * 8);
  f16x8 aq1 = *(const f16x8*)(qg + lcol * 64 + 32 + quad * 8);
  f16x8 bk0 = *(const f16x8*)(kg + lcol * 64 + quad * 8);
  f16x8 bk1 = *(const f16x8*)(kg + lcol * 64 + 32 + quad * 8);
  float p4[4];
#pragma unroll
  for (int r = 0; r < 4; r++) p4[r] = pat[(quad * 4 + r) * 16 + lcol];

  // Scatter V transposed into Vt[d][g] (wave-private, no barrier needed).
#pragma unroll
  for (int i = 0; i < 2; i++) {
    const int g = (ln >> 3) + i * 8, c = (ln & 7) * 8;
#pragma unroll
    for (int j = 0; j < 8; j++) Vt[wv][(c + j) * 24 + g] = vc[i][j];
  }

  // QK^T: A[m=h=lcol][k=quad*8+j], B[n=g=lcol][k=quad*8+j]
  f32x4 s = {0.f, 0.f, 0.f, 0.f};
  s = __builtin_amdgcn_mfma_f32_16x16x32_f16(aq0, bk0, s, 0, 0, 0);
  s = __builtin_amdgcn_mfma_f32_16x16x32_f16(aq1, bk1, s, 0, 0, 0);

  // lane holds scores[h=quad*4+r][g=lcol]; mask, softmax over g (16 lanes)
#pragma unroll
  for (int r = 0; r < 4; r++) {
    const float sv = s[r] * p4[r];
    float m = sv;
#pragma unroll
    for (int msk = 1; msk < 16; msk <<= 1) m = fmaxf(m, __shfl_xor(m, msk, 64));
    const float e = __expf(sv - m);
    float su = e;
#pragma unroll
    for (int msk = 1; msk < 16; msk <<= 1) su += __shfl_xor(su, msk, 64);
    Ps[wv][(quad * 4 + r) * 24 + lcol] = (_Float16)(e / su);
  }

  // PV with 16x16x16 (K=16): A[m=h=lcol][k=g=quad*4+j] from Ps;
  // B[n=d][k=g=quad*4+j] from Vt. All lanes active.
  f16x4 ap = *(const f16x4*)&Ps[wv][lcol * 24 + quad * 4];

  f32x4 o[4];
#pragma unroll
  for (int dt = 0; dt < 4; dt++) {
    f16x4 bvf = *(const f16x4*)&Vt[wv][(dt * 16 + lcol) * 24 + quad * 4];
    f32x4 z = {0.f, 0.f, 0.f, 0.f};
    o[dt] = __builtin_amdgcn_mfma_f32_16x16x16f16(ap, bvf, z, 0, 0, 0);
  }

  // C layout: row h=quad*4+r, col d=dt*16+lcol. dt innermost: 4 consecutive
  // 64B pieces of one 256B row region per (r).
  float* op = out + (size_t)t * 1024;
#pragma unroll
  for (int r = 0; r < 4; r++) {
    float* rp = op + (quad * 4 + r) * 64 + lcol;
#pragma unroll
    for (int dt = 0; dt < 4; dt++)
      rp[dt * 16] = o[dt][r];
  }
}

extern "C" void kernel_launch(void* const* d_in, const int* in_sizes, int n_in,
                              void* d_out, int out_size, void* d_ws, size_t ws_size,
                              hipStream_t stream) {
  const float* x   = (const float*)d_in[0];
  const float* pat = (const float*)d_in[1];
  const float* Wq  = (const float*)d_in[2];
  const float* bq  = (const float*)d_in[3];
  const float* Wk  = (const float*)d_in[4];
  const float* bk  = (const float*)d_in[5];
  const float* Wv  = (const float*)d_in[6];
  const float* bv  = (const float*)d_in[7];

  // ws layout (f16 elements):
  //   qkvh [16384][3][1024]  @ 0           (96 MiB)
  //   xh   [16384][1024]     @ 50331648    (32 MiB)
  //   wh   [3][1024][1024]   @ 67108864    ( 6 MiB)   total ~134 MiB
  _Float16* qkvh = (_Float16*)d_ws;
  _Float16* xh   = qkvh + (size_t)50331648;
  _Float16* wh   = qkvh + (size_t)67108864;

  cvt_f32_f16<<<4096, 256, 0, stream>>>(x, xh, 4194304);
  cvt3_f32_f16<<<dim3(256, 3), 256, 0, stream>>>(Wq, Wk, Wv, wh, 262144);

  // 64 m-tiles x 12 n-tiles = 768 blocks, 512 threads (8 waves)
  gemm_qkv<<<768, 512, 0, stream>>>(xh, wh, bq, bk, bv, qkvh);
  attn_kernel<<<M_ / 4, 256, 0, stream>>>(qkvh, pat, (float*)d_out);
}

// Round 9
// 268.364 us; speedup vs baseline: 1.1512x; 1.1102x over previous
//
#include <hip/hip_runtime.h>
#include <hip/hip_bf16.h>

#define M_   16384   // B*N tokens
#define K_   1024    // E
#define NQKV 3072    // 3*E output cols

typedef _Float16 f16x4 __attribute__((ext_vector_type(4)));
typedef _Float16 f16x8 __attribute__((ext_vector_type(8)));
typedef float    f32x4 __attribute__((ext_vector_type(4)));

// Fused fp32->fp16 convert: x (4194304 float4 chunks) then Wq/Wk/Wv
// (262144 chunks each). One launch instead of two.
__global__ __launch_bounds__(256) void cvt_all(
    const float* __restrict__ x,  const float* __restrict__ Wq,
    const float* __restrict__ Wk, const float* __restrict__ Wv,
    _Float16* __restrict__ xh, _Float16* __restrict__ wh) {
  int i = blockIdx.x * blockDim.x + threadIdx.x;
  const int stride = gridDim.x * blockDim.x;
  for (; i < 4980736; i += stride) {
    const float* src; _Float16* dst; int idx;
    if (i < 4194304) { src = x; dst = xh; idx = i; }
    else {
      const int j = i - 4194304, sel = j >> 18; idx = j & 262143;
      src = (sel == 0) ? Wq : (sel == 1) ? Wk : Wv;
      dst = wh + (size_t)sel * 1048576;
    }
    float4 v = ((const float4*)src)[idx];
    f16x4 h; h[0] = (_Float16)v.x; h[1] = (_Float16)v.y;
    h[2] = (_Float16)v.z; h[3] = (_Float16)v.w;
    *(f16x4*)&dst[(size_t)idx * 4] = h;
  }
}

// 256x256-tile GEMM, BK=32, double-buffered LDS (64KB), 1 barrier/K-tile.
// REGISTER BUDGET (R5/R7/R8 lesson): acc[8][4]=128 AGPR pins the unified
// 256/wave cap at 2 waves/SIMD -> arch-VGPR budget is EXACTLY 128. BK=64
// needed 96 frag VGPRs and any schedule with all frags live + staging temps
// spilled (phantom FETCH/WRITE). BK=32 halves frags to 48 (b[4],alo[4],
// ahi[4]) -> the issue-all-reads + counted-lgkm schedule fits with slack.
// Per K-tile: 12 ds_read_b128 | stage 4 gload_lds(t+1 -> buf^1) |
//   lgkm(4) 16 MFMA (alo x b) | lgkm(0) 16 MFMA (ahi x b) | VM0 | BAR.
// Ledger: reads of buf^1 finished before BAR(t-1) -> stage at t is WAR-safe;
// staged t+1 consumed after all-waves VM0(t)+BAR(t); VM0 ~1300cyc after issue
// (> 900 HBM latency). 2-bit XOR swizzle blk^=(r&3) both-sides: fragment
// b128 reads hit 8 lanes per 4-bank group (balanced, conflict-free).
// Per-CU floors: MFMA 1242 cyc/tile, LDS 1408 -> ~70-80us vs R6's 117.
__global__ __launch_bounds__(512, 2) void gemm_qkv(
    const _Float16* __restrict__ xh, const _Float16* __restrict__ wh,
    const float* __restrict__ bq, const float* __restrict__ bk,
    const float* __restrict__ bv, _Float16* __restrict__ qkv)
{
  __shared__ __align__(16) _Float16 As[2][256 * 32];
  __shared__ __align__(16) _Float16 Bs[2][256 * 32];

  const int tid  = threadIdx.x;
  const int ln   = tid & 63;
  const int w    = tid >> 6;     // 0..7
  const int wm2  = w >> 2;       // 0..1  (M half: 128 rows)
  const int wn4  = w & 3;        // 0..3  (N quarter: 64 cols)
  const int lcol = ln & 15, quad = ln >> 4;

  const int bid = blockIdx.x;                   // 768 blocks
  const int swz = (bid & 7) * 96 + (bid >> 3);  // XCD-contiguous chunks
  const int m0 = (swz / 12) * 256;
  const int n0 = (swz % 12) * 256;

  f32x4 acc[8][4];   // [m-tile 0..7][n-tile 0..3], 128 AGPR
#pragma unroll
  for (int i = 0; i < 8; ++i)
#pragma unroll
    for (int j = 0; j < 4; ++j) acc[i][j] = f32x4{0.f, 0.f, 0.f, 0.f};

  f16x8 alo[4], ahi[4], b[4];    // 48 arch VGPR

  // Stage one 256x32 fp16 panel (16KB) = 2 gload_lds/thread. Chunk c holds
  // row r=c>>2, LDS block c&3 <- source block (c&3)^(r&3) (inverse swizzle,
  // linear dest). Dest base per wave-group is uniform; HW adds lane*16.
#define STAGE32(BUF, T, GPTR, ROW0, LDSARR)                                    \
  { _Pragma("unroll")                                                          \
    for (int j = 0; j < 2; ++j) {                                              \
      const int c  = j * 512 + tid;                                            \
      const int r  = c >> 2;                                                   \
      const int cb = (c & 3) ^ (r & 3);                                        \
      __builtin_amdgcn_global_load_lds(                                        \
          (const __attribute__((address_space(1))) void*)(                     \
              GPTR + (size_t)((ROW0) + r) * K_ + (T) * 32 + cb * 8),           \
          (__attribute__((address_space(3))) void*)(                           \
              &LDSARR[BUF][(j * 512 + w * 64) * 8]),                           \
          16, 0, 0);                                                           \
    } }

  // fragment reads: swizzled block = quad ^ (row&3)
#define RDB(BUF)                                                               \
  _Pragma("unroll")                                                            \
  for (int ni = 0; ni < 4; ++ni) {                                             \
    const int br = wn4 * 64 + ni * 16 + lcol;                                  \
    b[ni] = *(const f16x8*)&Bs[BUF][br * 32 + ((quad ^ (br & 3))) * 8];        \
  }
#define RDA(DST, BUF, H)                                                       \
  _Pragma("unroll")                                                            \
  for (int mi = 0; mi < 4; ++mi) {                                             \
    const int ar = wm2 * 128 + (H) * 64 + mi * 16 + lcol;                      \
    DST[mi] = *(const f16x8*)&As[BUF][ar * 32 + ((quad ^ (ar & 3))) * 8];      \
  }

  // 16 MFMAs: one A-half (4 m-tiles) x all 4 n-tiles, K=32
#define MFMA16(AARR, H)                                                        \
  __builtin_amdgcn_s_setprio(1);                                               \
  _Pragma("unroll")                                                            \
  for (int mi = 0; mi < 4; ++mi)                                               \
    _Pragma("unroll")                                                          \
    for (int ni = 0; ni < 4; ++ni)                                             \
      acc[(H) * 4 + mi][ni] = __builtin_amdgcn_mfma_f32_16x16x32_f16(          \
          AARR[mi], b[ni], acc[(H) * 4 + mi][ni], 0, 0, 0);                    \
  __builtin_amdgcn_s_setprio(0);

#define SB()    __builtin_amdgcn_sched_barrier(0)
#define BAR()   { __builtin_amdgcn_s_barrier(); SB(); }
#define LGKM(N) { asm volatile("s_waitcnt lgkmcnt(" #N ")" ::: "memory"); SB(); }
#define VM0()   { asm volatile("s_waitcnt vmcnt(0)" ::: "memory"); SB(); }

#define KTILE(CUR, T, NOTLAST)                                                 \
  { RDB(CUR); RDA(alo, CUR, 0); RDA(ahi, CUR, 1); SB();   /* 12 reads */       \
    if (NOTLAST) {                                                             \
      STAGE32(1 - (CUR), (T) + 1, xh, m0, As);                                 \
      STAGE32(1 - (CUR), (T) + 1, wh, n0, Bs); SB();                           \
    }                                                                          \
    LGKM(4); MFMA16(alo, 0);   /* b+alo done; ahi drains under these */        \
    LGKM(0); MFMA16(ahi, 1);                                                   \
    if (NOTLAST) { VM0(); }                                                    \
    BAR(); }

  // Prologue: stage tile 0 into buf0, drain, barrier.
  STAGE32(0, 0, xh, m0, As); STAGE32(0, 0, wh, n0, Bs);
  VM0(); BAR();

#pragma unroll 1
  for (int it = 0; it < 15; ++it) {
    KTILE(0, it * 2,     1);
    KTILE(1, it * 2 + 1, 1);
  }
  KTILE(0, 30, 1);
  KTILE(1, 31, 0);

  // Epilogue. C/D: col=lane&15, row=quad*4+reg. mt -> r -> nt: a quad's 4
  // nt-stores (32B each) are back-to-back covering one 128B line (R6 win).
  float bi4[4];
#pragma unroll
  for (int nt = 0; nt < 4; ++nt) {
    const int col = n0 + wn4 * 64 + nt * 16 + lcol;
    const int seg = col >> 10, cs = col & 1023;
    bi4[nt] = ((seg == 0) ? bq : (seg == 1) ? bk : bv)[cs];
  }
#pragma unroll
  for (int mt = 0; mt < 8; ++mt) {
    const int r0 = m0 + wm2 * 128 + mt * 16 + quad * 4;
#pragma unroll
    for (int r = 0; r < 4; ++r) {
      _Float16* rowp = qkv + (size_t)(r0 + r) * 3072 + n0 + wn4 * 64 + lcol;
#pragma unroll
      for (int nt = 0; nt < 4; ++nt)
        rowp[nt * 16] = (_Float16)(acc[mt][nt][r] + bi4[nt]);
    }
  }
#undef STAGE32
#undef RDB
#undef RDA
#undef MFMA16
#undef SB
#undef BAR
#undef LGKM
#undef VM0
#undef KTILE
}

// One wave per token. qkv [token][3][1024] fp16. All global loads hoisted;
// pat read directly from global (L2-hot, no LDS/sync); PV uses 16x16x16 MFMA
// (K=16 exact: all 64 lanes active). Output stores: dt INNERMOST so each
// quad-row's 4x64B stores are consecutive (full-line write coalescing).
__global__ __launch_bounds__(256) void attn_kernel(
    const _Float16* __restrict__ qkv,
    const float* __restrict__ pat,
    float* __restrict__ out)
{
  __shared__ __align__(16) _Float16 Ps[4][16 * 24];  // P[h][g], stride 24
  __shared__ __align__(16) _Float16 Vt[4][64 * 24];  // V^T[d][g], stride 24

  const int tid  = threadIdx.x;
  const int ln   = tid & 63;
  const int wv   = tid >> 6;
  const int lcol = ln & 15, quad = ln >> 4;
  const int t    = blockIdx.x * 4 + wv;

  const _Float16* qg = qkv + (size_t)t * 3072;
  const _Float16* kg = qg + 1024;
  const _Float16* vg = qg + 2048;

  // Issue every global load up front: V (2), Q (2), K (2), pat (4 scalar).
  f16x8 vc[2];
  vc[0] = *(const f16x8*)(vg + ((ln >> 3)    ) * 64 + (ln & 7) * 8);
  vc[1] = *(const f16x8*)(vg + ((ln >> 3) + 8) * 64 + (ln & 7) * 8);
  f16x8 aq0 = *(const f16x8*)(qg + lcol * 64 + quad * 8);
  f16x8 aq1 = *(const f16x8*)(qg + lcol * 64 + 32 + quad * 8);
  f16x8 bk0 = *(const f16x8*)(kg + lcol * 64 + quad * 8);
  f16x8 bk1 = *(const f16x8*)(kg + lcol * 64 + 32 + quad * 8);
  float p4[4];
#pragma unroll
  for (int r = 0; r < 4; r++) p4[r] = pat[(quad * 4 + r) * 16 + lcol];

  // Scatter V transposed into Vt[d][g] (wave-private, no barrier needed).
#pragma unroll
  for (int i = 0; i < 2; i++) {
    const int g = (ln >> 3) + i * 8, c = (ln & 7) * 8;
#pragma unroll
    for (int j = 0; j < 8; j++) Vt[wv][(c + j) * 24 + g] = vc[i][j];
  }

  // QK^T: A[m=h=lcol][k=quad*8+j], B[n=g=lcol][k=quad*8+j]
  f32x4 s = {0.f, 0.f, 0.f, 0.f};
  s = __builtin_amdgcn_mfma_f32_16x16x32_f16(aq0, bk0, s, 0, 0, 0);
  s = __builtin_amdgcn_mfma_f32_16x16x32_f16(aq1, bk1, s, 0, 0, 0);

  // lane holds scores[h=quad*4+r][g=lcol]; mask, softmax over g (16 lanes)
#pragma unroll
  for (int r = 0; r < 4; r++) {
    const float sv = s[r] * p4[r];
    float m = sv;
#pragma unroll
    for (int msk = 1; msk < 16; msk <<= 1) m = fmaxf(m, __shfl_xor(m, msk, 64));
    const float e = __expf(sv - m);
    float su = e;
#pragma unroll
    for (int msk = 1; msk < 16; msk <<= 1) su += __shfl_xor(su, msk, 64);
    Ps[wv][(quad * 4 + r) * 24 + lcol] = (_Float16)(e / su);
  }

  // PV with 16x16x16 (K=16): A[m=h=lcol][k=g=quad*4+j] from Ps;
  // B[n=d][k=g=quad*4+j] from Vt. All lanes active.
  f16x4 ap = *(const f16x4*)&Ps[wv][lcol * 24 + quad * 4];

  f32x4 o[4];
#pragma unroll
  for (int dt = 0; dt < 4; dt++) {
    f16x4 bvf = *(const f16x4*)&Vt[wv][(dt * 16 + lcol) * 24 + quad * 4];
    f32x4 z = {0.f, 0.f, 0.f, 0.f};
    o[dt] = __builtin_amdgcn_mfma_f32_16x16x16f16(ap, bvf, z, 0, 0, 0);
  }

  // C layout: row h=quad*4+r, col d=dt*16+lcol. dt innermost: 4 consecutive
  // 64B pieces of one 256B row region per (r).
  float* op = out + (size_t)t * 1024;
#pragma unroll
  for (int r = 0; r < 4; r++) {
    float* rp = op + (quad * 4 + r) * 64 + lcol;
#pragma unroll
    for (int dt = 0; dt < 4; dt++)
      rp[dt * 16] = o[dt][r];
  }
}

extern "C" void kernel_launch(void* const* d_in, const int* in_sizes, int n_in,
                              void* d_out, int out_size, void* d_ws, size_t ws_size,
                              hipStream_t stream) {
  const float* x   = (const float*)d_in[0];
  const float* pat = (const float*)d_in[1];
  const float* Wq  = (const float*)d_in[2];
  const float* bq  = (const float*)d_in[3];
  const float* Wk  = (const float*)d_in[4];
  const float* bk  = (const float*)d_in[5];
  const float* Wv  = (const float*)d_in[6];
  const float* bv  = (const float*)d_in[7];

  // ws layout (f16 elements):
  //   qkvh [16384][3][1024]  @ 0           (96 MiB)
  //   xh   [16384][1024]     @ 50331648    (32 MiB)
  //   wh   [3][1024][1024]   @ 67108864    ( 6 MiB)   total ~134 MiB
  _Float16* qkvh = (_Float16*)d_ws;
  _Float16* xh   = qkvh + (size_t)50331648;
  _Float16* wh   = qkvh + (size_t)67108864;

  cvt_all<<<4096, 256, 0, stream>>>(x, Wq, Wk, Wv, xh, wh);

  // 64 m-tiles x 12 n-tiles = 768 blocks, 512 threads (8 waves)
  gemm_qkv<<<768, 512, 0, stream>>>(xh, wh, bq, bk, bv, qkvh);
  attn_kernel<<<M_ / 4, 256, 0, stream>>>(qkvh, pat, (float*)d_out);
}